// Round 2
// baseline (259.433 us; speedup 1.0000x reference)
//
#include <hip/hip_runtime.h>

typedef __bf16 bf16;
typedef _Float16 f16;
typedef __bf16 bf16x8 __attribute__((ext_vector_type(8)));
typedef _Float16 f16x8 __attribute__((ext_vector_type(8)));
typedef float f32x4 __attribute__((ext_vector_type(4)));

#define NROWS 4096
#define DIN 1024
#define DA 512

template <typename T> struct V8;
template <> struct V8<f16> { using type = f16x8; };
template <> struct V8<bf16> { using type = bf16x8; };

__device__ __forceinline__ f32x4 mfma16(f16x8 a, f16x8 b, f32x4 c) {
  return __builtin_amdgcn_mfma_f32_16x16x32_f16(a, b, c, 0, 0, 0);
}
__device__ __forceinline__ f32x4 mfma16(bf16x8 a, bf16x8 b, f32x4 c) {
  return __builtin_amdgcn_mfma_f32_16x16x32_bf16(a, b, c, 0, 0, 0);
}

__device__ __forceinline__ void gload_lds16(const void* g, void* l) {
  __builtin_amdgcn_global_load_lds((const __attribute__((address_space(1))) void*)g,
                                   (__attribute__((address_space(3))) void*)l, 16, 0, 0);
}

// ---------------- prep kernels ----------------

__global__ void cast_kernel(const float* __restrict__ s1, const float* __restrict__ s2,
                            f16* __restrict__ d1, f16* __restrict__ d2, int n) {
  const float* s = blockIdx.z ? s2 : s1;
  f16* d = blockIdx.z ? d2 : d1;
  int i = (blockIdx.x * blockDim.x + threadIdx.x) * 4;
  if (i < n) {
    float4 v = *(const float4*)(s + i);
    f16 o0 = (f16)v.x, o1 = (f16)v.y, o2 = (f16)v.z, o3 = (f16)v.w;
    f16x8 pack;  // store 4
    typedef _Float16 f16x4v __attribute__((ext_vector_type(4)));
    f16x4v o; o[0] = o0; o[1] = o1; o[2] = o2; o[3] = o3;
    *(f16x4v*)(d + i) = o;
    (void)pack;
  }
}

// dst[c][r] = (f16) src[r][c]  — fp32 weights -> transposed fp16
__global__ void transpose_f32(const float* __restrict__ w0, const float* __restrict__ w1,
                              const float* __restrict__ w2, f16* __restrict__ dst,
                              size_t dstride, int rows, int cols) {
  const float* s = blockIdx.z == 0 ? w0 : (blockIdx.z == 1 ? w1 : w2);
  f16* d = dst + (size_t)blockIdx.z * dstride;
  __shared__ float tile[32][33];
  int bc = blockIdx.x * 32, br = blockIdx.y * 32;
  int tx = threadIdx.x, ty = threadIdx.y;
  for (int i = ty; i < 32; i += 8)
    tile[i][tx] = s[(size_t)(br + i) * cols + bc + tx];
  __syncthreads();
  for (int i = ty; i < 32; i += 8)
    d[(size_t)(bc + i) * rows + br + tx] = (f16)tile[tx][i];
}

// bf16 [rows,cols] -> bf16 [cols][rows]
__global__ void transpose_b16(const bf16* __restrict__ src, size_t sstride,
                              bf16* __restrict__ dst, size_t dstride, int rows, int cols) {
  const bf16* s = src + (size_t)blockIdx.z * sstride;
  bf16* d = dst + (size_t)blockIdx.z * dstride;
  __shared__ float tile[32][33];
  int bc = blockIdx.x * 32, br = blockIdx.y * 32;
  int tx = threadIdx.x, ty = threadIdx.y;
  for (int i = ty; i < 32; i += 8)
    tile[i][tx] = (float)s[(size_t)(br + i) * cols + bc + tx];
  __syncthreads();
  for (int i = ty; i < 32; i += 8)
    d[(size_t)(bc + i) * rows + br + tx] = (bf16)tile[tx][i];
}

// ---------------- GEMM ----------------
// C[M,N] = A[M,K] @ Bt[N,K]^T, 128x128 tile, BK=64, 4 waves (2x2), 16x16x32 MFMA.
// EPI 0: +bias      EPI 1: exp()      EPI 2: /rowsum(A-row)
// TIN: operand dtype (f16 or bf16), TOUT: store dtype (f16, bf16, float)

template <typename TIN>
struct GArgs {
  const TIN* A[6];
  const TIN* B[6];
  const float* bias[6];
  void* C[6];
  int K, lda, ldb, ldc;
};

template <typename TIN, typename TOUT, int EPI>
__global__ __launch_bounds__(256) void gemm_bt(GArgs<TIN> args) {
  using vec8 = typename V8<TIN>::type;
  __shared__ __align__(16) TIN As[128 * 64];
  __shared__ __align__(16) TIN Bs[128 * 64];

  const int z = blockIdx.z;
  const TIN* __restrict__ Ag = args.A[z];
  const TIN* __restrict__ Bg = args.B[z];
  const float* __restrict__ bias = args.bias[z];
  void* Cg = args.C[z];
  const int K = args.K;
  const int lda = args.lda, ldb = args.ldb, ldc = args.ldc;

  const int tid = threadIdx.x;
  const int w = tid >> 6, lane = tid & 63;
  const int wr = w >> 1, wc = w & 1;
  const int lrow = lane & 15, lhi = lane >> 4;
  const int blkM = blockIdx.y, blkN = blockIdx.x;

  const TIN* Abase = Ag + (size_t)blkM * 128 * lda;
  const TIN* Bbase = Bg + (size_t)blkN * 128 * ldb;

  f32x4 acc[4][4] = {};
  f32x4 rs[4] = {};
  vec8 ones;
  if (EPI == 2) {
#pragma unroll
    for (int i = 0; i < 8; ++i) ones[i] = (TIN)1.0f;
  }

  for (int kt = 0; kt < K; kt += 64) {
#pragma unroll
    for (int it = 0; it < 4; ++it) {
      int grp = it * 4 + w;                 // 0..15, wave-uniform
      int chunk = grp * 64 + lane;          // 16B chunks
      int row = chunk >> 3;
      int col = (chunk & 7) << 3;
      gload_lds16(Abase + (size_t)row * lda + kt + col, (char*)As + (size_t)grp * 1024);
      gload_lds16(Bbase + (size_t)row * ldb + kt + col, (char*)Bs + (size_t)grp * 1024);
    }
    __syncthreads();

    vec8 af[4][2], bfr[4][2];
#pragma unroll
    for (int m = 0; m < 4; ++m)
#pragma unroll
      for (int kk = 0; kk < 2; ++kk)
        af[m][kk] = *(const vec8*)&As[(wr * 64 + m * 16 + lrow) * 64 + kk * 32 + lhi * 8];
#pragma unroll
    for (int n = 0; n < 4; ++n)
#pragma unroll
      for (int kk = 0; kk < 2; ++kk)
        bfr[n][kk] = *(const vec8*)&Bs[(wc * 64 + n * 16 + lrow) * 64 + kk * 32 + lhi * 8];

#pragma unroll
    for (int m = 0; m < 4; ++m)
#pragma unroll
      for (int n = 0; n < 4; ++n)
#pragma unroll
        for (int kk = 0; kk < 2; ++kk)
          acc[m][n] = mfma16(af[m][kk], bfr[n][kk], acc[m][n]);

    if (EPI == 2) {
#pragma unroll
      for (int m = 0; m < 4; ++m)
#pragma unroll
        for (int kk = 0; kk < 2; ++kk)
          rs[m] = mfma16(af[m][kk], ones, rs[m]);
    }
    __syncthreads();
  }

  const int row0 = blkM * 128 + wr * 64;
  const int col0 = blkN * 128 + wc * 64;
#pragma unroll
  for (int m = 0; m < 4; ++m) {
#pragma unroll
    for (int n = 0; n < 4; ++n) {
#pragma unroll
      for (int r = 0; r < 4; ++r) {
        int row = row0 + m * 16 + lhi * 4 + r;
        int col = col0 + n * 16 + lrow;
        float v = acc[m][n][r];
        if (EPI == 0) {
          ((TOUT*)Cg)[(size_t)row * ldc + col] = (TOUT)(v + bias[col]);
        } else if (EPI == 1) {
          ((TOUT*)Cg)[(size_t)row * ldc + col] = (TOUT)__expf(v);
        } else {
          ((TOUT*)Cg)[(size_t)row * ldc + col] = (TOUT)(v / rs[m][r]);
        }
      }
    }
  }
}

// ---------------- launch ----------------

extern "C" void kernel_launch(void* const* d_in, const int* in_sizes, int n_in,
                              void* d_out, int out_size, void* d_ws, size_t ws_size,
                              hipStream_t stream) {
  const float* in1 = (const float*)d_in[0];
  const float* in2 = (const float*)d_in[1];
  const float* Wq = (const float*)d_in[2];
  const float* bq = (const float*)d_in[3];
  const float* Wk = (const float*)d_in[4];
  const float* bk = (const float*)d_in[5];
  const float* Wv = (const float*)d_in[6];
  const float* bv = (const float*)d_in[7];
  const float* Wo = (const float*)d_in[8];
  const float* bo = (const float*)d_in[9];
  float* out = (float*)d_out;

  const size_t IN_E = (size_t)NROWS * DIN;   // 4M
  const size_t WT_E = (size_t)DA * DIN;      // 512K
  const size_t QS = (size_t)NROWS * DA;      // 2M
  const size_t PS = (size_t)NROWS * NROWS;   // 16M

  f16* in_hf = (f16*)d_ws;                   // 2*IN_E
  f16* wt = in_hf + 2 * IN_E;                // 3*WT_E (WqT,WkT,WvT [512][1024] f16)
  f16* woT = wt + 3 * WT_E;                  // [1024][512] f16
  f16* qk = woT + WT_E;                      // Q1,K1,Q2,K2 : 4*QS f16
  bf16* vv = (bf16*)(qk + 4 * QS);           // V1,V2 : 2*QS bf16
  bf16* vt = vv + 2 * QS;                    // V1t,V2t : 2*QS bf16
  bf16* P = vt + 2 * QS;                     // 2*PS bf16
  f16* mid = (f16*)(P + 2 * PS);             // 2*QS f16

  // 1. cast inputs to fp16
  cast_kernel<<<dim3((unsigned)(IN_E / 1024), 1, 2), dim3(256), 0, stream>>>(
      in1, in2, in_hf, in_hf + IN_E, (int)IN_E);

  // 2. transpose-cast weights
  transpose_f32<<<dim3(DA / 32, DIN / 32, 3), dim3(32, 8), 0, stream>>>(
      Wq, Wk, Wv, wt, WT_E, DIN, DA);
  transpose_f32<<<dim3(DIN / 32, DA / 32, 1), dim3(32, 8), 0, stream>>>(
      Wo, Wo, Wo, woT, 0, DA, DIN);

  // 3a. Q/K projections (f16 out): z: Q1, K1, Q2, K2
  {
    GArgs<f16> a{};
    for (int zi = 0; zi < 4; ++zi) {
      a.A[zi] = in_hf + (size_t)(zi >> 1) * IN_E;
      a.B[zi] = wt + (size_t)(zi & 1) * WT_E;
      a.bias[zi] = (zi & 1) ? bk : bq;
      a.C[zi] = qk + (size_t)zi * QS;
    }
    a.K = DIN; a.lda = DIN; a.ldb = DIN; a.ldc = DA;
    gemm_bt<f16, f16, 0><<<dim3(DA / 128, NROWS / 128, 4), dim3(256), 0, stream>>>(a);
  }
  // 3b. V projections (bf16 out): z: V1, V2
  {
    GArgs<f16> a{};
    for (int zi = 0; zi < 2; ++zi) {
      a.A[zi] = in_hf + (size_t)zi * IN_E;
      a.B[zi] = wt + 2 * WT_E;
      a.bias[zi] = bv;
      a.C[zi] = vv + (size_t)zi * QS;
    }
    a.K = DIN; a.lda = DIN; a.ldb = DIN; a.ldc = DA;
    gemm_bt<f16, bf16, 0><<<dim3(DA / 128, NROWS / 128, 2), dim3(256), 0, stream>>>(a);
  }

  // 4. V -> Vt ([4096,512] -> [512][4096])
  transpose_b16<<<dim3(DA / 32, NROWS / 32, 2), dim3(32, 8), 0, stream>>>(
      vv, QS, vt, QS, NROWS, DA);

  // 5. P = exp(Q @ K^T): z=0: Q1@K2^T, z=1: Q2@K1^T  (bf16 out — exp range)
  {
    GArgs<f16> a{};
    a.A[0] = qk + 0 * QS; a.B[0] = qk + 3 * QS; a.C[0] = P;
    a.A[1] = qk + 2 * QS; a.B[1] = qk + 1 * QS; a.C[1] = P + PS;
    a.bias[0] = a.bias[1] = nullptr;
    a.K = DA; a.lda = DA; a.ldb = DA; a.ldc = NROWS;
    gemm_bt<f16, bf16, 1><<<dim3(NROWS / 128, NROWS / 128, 2), dim3(256), 0, stream>>>(a);
  }

  // 6. mid = (P @ V) / rowsum(P): z=0: P1@V2, z=1: P2@V1  (f16 out)
  {
    GArgs<bf16> a{};
    a.A[0] = P;      a.B[0] = vt + QS; a.C[0] = mid;
    a.A[1] = P + PS; a.B[1] = vt;      a.C[1] = mid + QS;
    a.bias[0] = a.bias[1] = nullptr;
    a.K = NROWS; a.lda = NROWS; a.ldb = NROWS; a.ldc = DA;
    gemm_bt<bf16, f16, 2><<<dim3(DA / 128, NROWS / 128, 2), dim3(256), 0, stream>>>(a);
  }

  // 7. out = mid @ Wo + bo (f32 out)
  {
    GArgs<f16> a{};
    a.A[0] = mid;      a.C[0] = out;
    a.A[1] = mid + QS; a.C[1] = out + (size_t)NROWS * DIN;
    a.B[0] = a.B[1] = woT;
    a.bias[0] = a.bias[1] = bo;
    a.K = DA; a.lda = DA; a.ldb = DA; a.ldc = DIN;
    gemm_bt<f16, float, 0><<<dim3(DIN / 128, NROWS / 128, 2), dim3(256), 0, stream>>>(a);
  }
}

// Round 3
// 216.316 us; speedup vs baseline: 1.1993x; 1.1993x over previous
//
#include <hip/hip_runtime.h>

typedef __bf16 bf16;
typedef _Float16 f16;
typedef __bf16 bf16x8 __attribute__((ext_vector_type(8)));
typedef _Float16 f16x8 __attribute__((ext_vector_type(8)));
typedef _Float16 f16x4 __attribute__((ext_vector_type(4)));
typedef float f32x4 __attribute__((ext_vector_type(4)));

#define NROWS 4096
#define DIN 1024
#define DA 512

template <typename T> struct V8;
template <> struct V8<f16> { using type = f16x8; };
template <> struct V8<bf16> { using type = bf16x8; };

__device__ __forceinline__ f32x4 mfma16(f16x8 a, f16x8 b, f32x4 c) {
  return __builtin_amdgcn_mfma_f32_16x16x32_f16(a, b, c, 0, 0, 0);
}
__device__ __forceinline__ f32x4 mfma16(bf16x8 a, bf16x8 b, f32x4 c) {
  return __builtin_amdgcn_mfma_f32_16x16x32_bf16(a, b, c, 0, 0, 0);
}

__device__ __forceinline__ void gload_lds16(const void* g, void* l) {
  __builtin_amdgcn_global_load_lds((const __attribute__((address_space(1))) void*)g,
                                   (__attribute__((address_space(3))) void*)l, 16, 0, 0);
}

// ---------------- prep kernels ----------------

__global__ void cast_kernel(const float* __restrict__ s1, const float* __restrict__ s2,
                            f16* __restrict__ d1, f16* __restrict__ d2, int n) {
  const float* s = blockIdx.z ? s2 : s1;
  f16* d = blockIdx.z ? d2 : d1;
  int i = (blockIdx.x * blockDim.x + threadIdx.x) * 4;
  if (i < n) {
    float4 v = *(const float4*)(s + i);
    f16x4 o;
    o[0] = (f16)v.x; o[1] = (f16)v.y; o[2] = (f16)v.z; o[3] = (f16)v.w;
    *(f16x4*)(d + i) = o;
  }
}

// dst[c][r] = (f16) src[r][c]
__global__ void transpose_f32(const float* __restrict__ w0, const float* __restrict__ w1,
                              const float* __restrict__ w2, f16* __restrict__ dst,
                              size_t dstride, int rows, int cols) {
  const float* s = blockIdx.z == 0 ? w0 : (blockIdx.z == 1 ? w1 : w2);
  f16* d = dst + (size_t)blockIdx.z * dstride;
  __shared__ float tile[32][33];
  int bc = blockIdx.x * 32, br = blockIdx.y * 32;
  int tx = threadIdx.x, ty = threadIdx.y;
  for (int i = ty; i < 32; i += 8)
    tile[i][tx] = s[(size_t)(br + i) * cols + bc + tx];
  __syncthreads();
  for (int i = ty; i < 32; i += 8)
    d[(size_t)(bc + i) * rows + br + tx] = (f16)tile[tx][i];
}

// bf16 [rows,cols] -> bf16 [cols][rows]
__global__ void transpose_b16(const bf16* __restrict__ src, size_t sstride,
                              bf16* __restrict__ dst, size_t dstride, int rows, int cols) {
  const bf16* s = src + (size_t)blockIdx.z * sstride;
  bf16* d = dst + (size_t)blockIdx.z * dstride;
  __shared__ float tile[32][33];
  int bc = blockIdx.x * 32, br = blockIdx.y * 32;
  int tx = threadIdx.x, ty = threadIdx.y;
  for (int i = ty; i < 32; i += 8)
    tile[i][tx] = (float)s[(size_t)(br + i) * cols + bc + tx];
  __syncthreads();
  for (int i = ty; i < 32; i += 8)
    d[(size_t)(bc + i) * rows + br + tx] = (bf16)tile[tx][i];
}

// merge split-K PV partials: mid = (pO[0]+pO[1]) / (rs[0]+rs[1]), f16
__global__ void merge_kernel(const float* __restrict__ pO, const float* __restrict__ prs,
                             f16* __restrict__ mid) {
  const size_t QS = (size_t)NROWS * DA;
  size_t e = ((size_t)blockIdx.x * blockDim.x + threadIdx.x) * 4;
  int z = (int)(e / QS);
  size_t rem = e - (size_t)z * QS;
  int row = (int)(rem / DA);
  float4 a = *(const float4*)(pO + (size_t)z * QS + rem);
  float4 b = *(const float4*)(pO + (size_t)(2 + z) * QS + rem);
  float rs = prs[z * NROWS + row] + prs[(2 + z) * NROWS + row];
  float inv = 1.0f / rs;
  f16x4 o;
  o[0] = (f16)((a.x + b.x) * inv);
  o[1] = (f16)((a.y + b.y) * inv);
  o[2] = (f16)((a.z + b.z) * inv);
  o[3] = (f16)((a.w + b.w) * inv);
  *(f16x4*)(mid + (size_t)z * QS + rem) = o;
}

// ---------------- GEMM ----------------
// C[M,N] = A[M,K_len] @ Bt[N,K_len]^T  (K window [k0, k0+K) of the full K dim)
// 128x128 tile, BK=64, 8 waves (2x4, each 64x32), 16x16x32 MFMA.
// EPI 0: +bias, store f16 or bf16 per storebf[z]
// EPI 1: exp(), store bf16
// EPI 2: split-K partial: store f32 raw acc to C, partial rowsum f32 to rsO
// EPI 3: +bias, store f32

template <typename TIN>
struct GArgs {
  const TIN* A[6];
  const TIN* B[6];
  const float* bias[6];
  void* C[6];
  float* rsO[6];
  int k0[6];
  int storebf[6];
  int K, lda, ldb, ldc;
};

template <typename TIN, typename TOUT, int EPI>
__global__ __launch_bounds__(512) void gemm_bt(GArgs<TIN> args) {
  using vec8 = typename V8<TIN>::type;
  __shared__ __align__(16) TIN As[128 * 64];
  __shared__ __align__(16) TIN Bs[128 * 64];

  const int z = blockIdx.z;
  const TIN* __restrict__ Ag = args.A[z];
  const TIN* __restrict__ Bg = args.B[z];
  const float* __restrict__ bias = args.bias[z];
  void* Cg = args.C[z];
  const int K = args.K, k0 = args.k0[z];
  const int lda = args.lda, ldb = args.ldb, ldc = args.ldc;

  const int tid = threadIdx.x;
  const int w = tid >> 6, lane = tid & 63;
  const int wr = w >> 2, wc = w & 3;
  const int lrow = lane & 15, lhi = lane >> 4;
  const int blkM = blockIdx.y, blkN = blockIdx.x;

  const TIN* Abase = Ag + (size_t)blkM * 128 * lda;
  const TIN* Bbase = Bg + (size_t)blkN * 128 * ldb;

  f32x4 acc[4][2] = {};
  f32x4 rs[4] = {};
  vec8 ones;
  if (EPI == 2) {
#pragma unroll
    for (int i = 0; i < 8; ++i) ones[i] = (TIN)1.0f;
  }

  for (int kt = k0; kt < k0 + K; kt += 64) {
#pragma unroll
    for (int it = 0; it < 2; ++it) {
      int grp = it * 8 + w;                 // 0..15, wave-uniform
      int chunk = grp * 64 + lane;          // 16B chunks
      int row = chunk >> 3;
      int col = (chunk & 7) << 3;
      gload_lds16(Abase + (size_t)row * lda + kt + col, (char*)As + (size_t)grp * 1024);
      gload_lds16(Bbase + (size_t)row * ldb + kt + col, (char*)Bs + (size_t)grp * 1024);
    }
    __syncthreads();

    vec8 af[4][2], bfr[2][2];
#pragma unroll
    for (int m = 0; m < 4; ++m)
#pragma unroll
      for (int kk = 0; kk < 2; ++kk)
        af[m][kk] = *(const vec8*)&As[(wr * 64 + m * 16 + lrow) * 64 + kk * 32 + lhi * 8];
#pragma unroll
    for (int n = 0; n < 2; ++n)
#pragma unroll
      for (int kk = 0; kk < 2; ++kk)
        bfr[n][kk] = *(const vec8*)&Bs[(wc * 32 + n * 16 + lrow) * 64 + kk * 32 + lhi * 8];

#pragma unroll
    for (int m = 0; m < 4; ++m)
#pragma unroll
      for (int n = 0; n < 2; ++n)
#pragma unroll
        for (int kk = 0; kk < 2; ++kk)
          acc[m][n] = mfma16(af[m][kk], bfr[n][kk], acc[m][n]);

    if (EPI == 2 && wc == 0) {
#pragma unroll
      for (int m = 0; m < 4; ++m)
#pragma unroll
        for (int kk = 0; kk < 2; ++kk)
          rs[m] = mfma16(af[m][kk], ones, rs[m]);
    }
    __syncthreads();
  }

  const int row0 = blkM * 128 + wr * 64;
  const int col0 = blkN * 128 + wc * 32;
  const int sbf = args.storebf[z];
#pragma unroll
  for (int m = 0; m < 4; ++m) {
#pragma unroll
    for (int n = 0; n < 2; ++n) {
#pragma unroll
      for (int r = 0; r < 4; ++r) {
        int row = row0 + m * 16 + lhi * 4 + r;
        int col = col0 + n * 16 + lrow;
        float v = acc[m][n][r];
        if (EPI == 0) {
          if (sbf)
            ((bf16*)Cg)[(size_t)row * ldc + col] = (bf16)(v + bias[col]);
          else
            ((f16*)Cg)[(size_t)row * ldc + col] = (f16)(v + bias[col]);
        } else if (EPI == 1) {
          ((bf16*)Cg)[(size_t)row * ldc + col] = (bf16)__expf(v);
        } else if (EPI == 2) {
          ((float*)Cg)[(size_t)row * ldc + col] = v;
        } else {
          ((float*)Cg)[(size_t)row * ldc + col] = v + bias[col];
        }
      }
    }
  }
  if (EPI == 2 && wc == 0 && lrow == 0) {
    float* rsO = args.rsO[z];
#pragma unroll
    for (int m = 0; m < 4; ++m)
#pragma unroll
      for (int r = 0; r < 4; ++r)
        rsO[row0 + m * 16 + lhi * 4 + r] = rs[m][r];
  }
}

// ---------------- launch ----------------

extern "C" void kernel_launch(void* const* d_in, const int* in_sizes, int n_in,
                              void* d_out, int out_size, void* d_ws, size_t ws_size,
                              hipStream_t stream) {
  const float* in1 = (const float*)d_in[0];
  const float* in2 = (const float*)d_in[1];
  const float* Wq = (const float*)d_in[2];
  const float* bq = (const float*)d_in[3];
  const float* Wk = (const float*)d_in[4];
  const float* bk = (const float*)d_in[5];
  const float* Wv = (const float*)d_in[6];
  const float* bv = (const float*)d_in[7];
  const float* Wo = (const float*)d_in[8];
  const float* bo = (const float*)d_in[9];
  float* out = (float*)d_out;

  const size_t IN_E = (size_t)NROWS * DIN;   // 4M
  const size_t WT_E = (size_t)DA * DIN;      // 512K
  const size_t QS = (size_t)NROWS * DA;      // 2M
  const size_t PS = (size_t)NROWS * NROWS;   // 16M

  // layout (so PV partials can alias dead buffers):
  f16* qk = (f16*)d_ws;                      // 4*QS f16 = 16 MB (dead after exp GEMM)
  f16* in_hf = qk + 4 * QS;                  // 2*IN_E f16 = 16 MB (dead after proj)
  bf16* vv = (bf16*)(in_hf + 2 * IN_E);      // 2*QS bf16 = 8 MB (dead after transpose)
  f16* wt = (f16*)(vv + 2 * QS);             // 3*WT_E f16 = 3 MB
  f16* woT = wt + 3 * WT_E;                  // WT_E f16 = 1 MB (live till end)
  bf16* vt = (bf16*)(woT + WT_E);            // 2*QS bf16 = 8 MB
  bf16* P = vt + 2 * QS;                     // 2*PS bf16 = 64 MB
  f16* mid = (f16*)(P + 2 * PS);             // 2*QS f16 = 8 MB
  float* pO = (float*)d_ws;                  // aliases qk+in_hf: 4*QS f32 = 32 MB
  float* prs = (float*)vv;                   // aliases vv: 4*NROWS f32 = 64 KB

  // 1. cast inputs to fp16
  cast_kernel<<<dim3((unsigned)(IN_E / 1024), 1, 2), dim3(256), 0, stream>>>(
      in1, in2, in_hf, in_hf + IN_E, (int)IN_E);

  // 2. transpose-cast weights
  transpose_f32<<<dim3(DA / 32, DIN / 32, 3), dim3(32, 8), 0, stream>>>(
      Wq, Wk, Wv, wt, WT_E, DIN, DA);
  transpose_f32<<<dim3(DIN / 32, DA / 32, 1), dim3(32, 8), 0, stream>>>(
      Wo, Wo, Wo, woT, 0, DA, DIN);

  // 3. projections, z = Q1,K1,Q2,K2,V1,V2 (V stored bf16)
  {
    GArgs<f16> a{};
    const float* bs[3] = {bq, bk, bv};
    for (int zi = 0; zi < 6; ++zi) {
      int which = (zi < 4) ? (zi & 1) : 2;        // wq/wk/wv
      int src = (zi < 4) ? (zi >> 1) : (zi - 4);  // input1/input2
      a.A[zi] = in_hf + (size_t)src * IN_E;
      a.B[zi] = wt + (size_t)which * WT_E;
      a.bias[zi] = bs[which];
      a.C[zi] = (zi < 4) ? (void*)(qk + (size_t)zi * QS) : (void*)(vv + (size_t)(zi - 4) * QS);
      a.storebf[zi] = (zi >= 4);
    }
    a.K = DIN; a.lda = DIN; a.ldb = DIN; a.ldc = DA;
    gemm_bt<f16, f16, 0><<<dim3(DA / 128, NROWS / 128, 6), dim3(512), 0, stream>>>(a);
  }

  // 4. V -> Vt ([4096,512] -> [512][4096])
  transpose_b16<<<dim3(DA / 32, NROWS / 32, 2), dim3(32, 8), 0, stream>>>(
      vv, QS, vt, QS, NROWS, DA);

  // 5. P = exp(Q @ K^T): z=0: Q1@K2^T, z=1: Q2@K1^T (bf16 out)
  {
    GArgs<f16> a{};
    a.A[0] = qk + 0 * QS; a.B[0] = qk + 3 * QS; a.C[0] = P;
    a.A[1] = qk + 2 * QS; a.B[1] = qk + 1 * QS; a.C[1] = P + PS;
    a.K = DA; a.lda = DA; a.ldb = DA; a.ldc = NROWS;
    gemm_bt<f16, bf16, 1><<<dim3(NROWS / 128, NROWS / 128, 2), dim3(512), 0, stream>>>(a);
  }

  // 6. PV split-K partials: z encodes (s = z>>1, pair = z&1)
  //    pO[s*2+pair] = P[pair][:, k-window] @ V[other][k-window]
  {
    GArgs<bf16> a{};
    for (int i = 0; i < 4; ++i) {
      int pair = i & 1, s = i >> 1;
      a.A[i] = P + (size_t)pair * PS;
      a.B[i] = vt + (size_t)(pair ^ 1) * QS;
      a.C[i] = pO + (size_t)i * QS;
      a.rsO[i] = prs + (size_t)i * NROWS;
      a.k0[i] = s * 2048;
    }
    a.K = 2048; a.lda = NROWS; a.ldb = NROWS; a.ldc = DA;
    gemm_bt<bf16, float, 2><<<dim3(DA / 128, NROWS / 128, 4), dim3(512), 0, stream>>>(a);
  }

  // 7. merge partials -> mid (f16)
  merge_kernel<<<dim3((unsigned)(2 * QS / 1024)), dim3(256), 0, stream>>>(pO, prs, mid);

  // 8. out = mid @ Wo + bo (f32)
  {
    GArgs<f16> a{};
    a.A[0] = mid;      a.C[0] = out;
    a.A[1] = mid + QS; a.C[1] = out + (size_t)NROWS * DIN;
    a.B[0] = a.B[1] = woT;
    a.bias[0] = a.bias[1] = bo;
    a.K = DA; a.lda = DA; a.ldb = DA; a.ldc = DIN;
    gemm_bt<f16, float, 3><<<dim3(DIN / 128, NROWS / 128, 2), dim3(512), 0, stream>>>(a);
  }
}

// Round 4
// 214.161 us; speedup vs baseline: 1.2114x; 1.0101x over previous
//
#include <hip/hip_runtime.h>

typedef __bf16 bf16;
typedef _Float16 f16;
typedef __bf16 bf16x8 __attribute__((ext_vector_type(8)));
typedef _Float16 f16x8 __attribute__((ext_vector_type(8)));
typedef _Float16 f16x4 __attribute__((ext_vector_type(4)));
typedef float f32x4 __attribute__((ext_vector_type(4)));

#define NROWS 4096
#define DIN 1024
#define DA 512

template <typename T> struct V8;
template <> struct V8<f16> { using type = f16x8; };
template <> struct V8<bf16> { using type = bf16x8; };

__device__ __forceinline__ f32x4 mfma16(f16x8 a, f16x8 b, f32x4 c) {
  return __builtin_amdgcn_mfma_f32_16x16x32_f16(a, b, c, 0, 0, 0);
}
__device__ __forceinline__ f32x4 mfma16(bf16x8 a, bf16x8 b, f32x4 c) {
  return __builtin_amdgcn_mfma_f32_16x16x32_bf16(a, b, c, 0, 0, 0);
}

__device__ __forceinline__ void gload_lds16(const void* g, void* l) {
  __builtin_amdgcn_global_load_lds((const __attribute__((address_space(1))) void*)g,
                                   (__attribute__((address_space(3))) void*)l, 16, 0, 0);
}

// ---------------- prep kernels ----------------

__global__ void cast_kernel(const float* __restrict__ s1, const float* __restrict__ s2,
                            f16* __restrict__ d1, f16* __restrict__ d2, int n) {
  const float* s = blockIdx.z ? s2 : s1;
  f16* d = blockIdx.z ? d2 : d1;
  int i = (blockIdx.x * blockDim.x + threadIdx.x) * 4;
  if (i < n) {
    float4 v = *(const float4*)(s + i);
    f16x4 o;
    o[0] = (f16)v.x; o[1] = (f16)v.y; o[2] = (f16)v.z; o[3] = (f16)v.w;
    *(f16x4*)(d + i) = o;
  }
}

// dst[c][r] = (f16) src[r][c]
__global__ void transpose_f32(const float* __restrict__ w0, const float* __restrict__ w1,
                              const float* __restrict__ w2, f16* __restrict__ dst,
                              size_t dstride, int rows, int cols) {
  const float* s = blockIdx.z == 0 ? w0 : (blockIdx.z == 1 ? w1 : w2);
  f16* d = dst + (size_t)blockIdx.z * dstride;
  __shared__ float tile[32][33];
  int bc = blockIdx.x * 32, br = blockIdx.y * 32;
  int tx = threadIdx.x, ty = threadIdx.y;
  for (int i = ty; i < 32; i += 8)
    tile[i][tx] = s[(size_t)(br + i) * cols + bc + tx];
  __syncthreads();
  for (int i = ty; i < 32; i += 8)
    d[(size_t)(bc + i) * rows + br + tx] = (f16)tile[tx][i];
}

// bf16 [rows,cols] -> bf16 [cols][rows]
__global__ void transpose_b16(const bf16* __restrict__ src, size_t sstride,
                              bf16* __restrict__ dst, size_t dstride, int rows, int cols) {
  const bf16* s = src + (size_t)blockIdx.z * sstride;
  bf16* d = dst + (size_t)blockIdx.z * dstride;
  __shared__ float tile[32][33];
  int bc = blockIdx.x * 32, br = blockIdx.y * 32;
  int tx = threadIdx.x, ty = threadIdx.y;
  for (int i = ty; i < 32; i += 8)
    tile[i][tx] = (float)s[(size_t)(br + i) * cols + bc + tx];
  __syncthreads();
  for (int i = ty; i < 32; i += 8)
    d[(size_t)(bc + i) * rows + br + tx] = (bf16)tile[tx][i];
}

// merge split-K PV partials: mid = (pO[0]+pO[1]) / (rs[0]+rs[1]), f16
__global__ void merge_kernel(const float* __restrict__ pO, const float* __restrict__ prs,
                             f16* __restrict__ mid) {
  const size_t QS = (size_t)NROWS * DA;
  size_t e = ((size_t)blockIdx.x * blockDim.x + threadIdx.x) * 4;
  int z = (int)(e / QS);
  size_t rem = e - (size_t)z * QS;
  int row = (int)(rem / DA);
  float4 a = *(const float4*)(pO + (size_t)z * QS + rem);
  float4 b = *(const float4*)(pO + (size_t)(2 + z) * QS + rem);
  float rs = prs[z * NROWS + row] + prs[(2 + z) * NROWS + row];
  float inv = 1.0f / rs;
  f16x4 o;
  o[0] = (f16)((a.x + b.x) * inv);
  o[1] = (f16)((a.y + b.y) * inv);
  o[2] = (f16)((a.z + b.z) * inv);
  o[3] = (f16)((a.w + b.w) * inv);
  *(f16x4*)(mid + (size_t)z * QS + rem) = o;
}

// ---------------- GEMM ----------------
// C[M,N] = A[M,K_len] @ Bt[N,K_len]^T  (K window [k0, k0+K) of the full K dim)
// 128x128 tile, BK=64, 8 waves (2x4, each 64x32), 16x16x32 MFMA.
// T1 XCD-aware bijective block swizzle (per-z grids are all %8==0).
// EPI 0: +bias, store f16 or bf16 per storebf[z]
// EPI 1: exp(), store bf16
// EPI 2: split-K partial: store f32 raw acc to C, partial rowsum f32 to rsO
// EPI 3: +bias, store f32

template <typename TIN>
struct GArgs {
  const TIN* A[6];
  const TIN* B[6];
  const float* bias[6];
  void* C[6];
  float* rsO[6];
  int k0[6];
  int storebf[6];
  int K, lda, ldb, ldc;
};

template <typename TIN, typename TOUT, int EPI>
__global__ __launch_bounds__(512) void gemm_bt(GArgs<TIN> args) {
  using vec8 = typename V8<TIN>::type;
  __shared__ __align__(16) TIN As[128 * 64];
  __shared__ __align__(16) TIN Bs[128 * 64];

  const int z = blockIdx.z;
  const TIN* __restrict__ Ag = args.A[z];
  const TIN* __restrict__ Bg = args.B[z];
  const float* __restrict__ bias = args.bias[z];
  void* Cg = args.C[z];
  const int K = args.K, k0 = args.k0[z];
  const int lda = args.lda, ldb = args.ldb, ldc = args.ldc;

  // T1: XCD-aware swizzle. HW round-robins linear block id across 8 XCDs;
  // remap so a contiguous chunk of logical tiles (sharing A-panels) lands
  // on one XCD's L2.
  int blkM, blkN;
  {
    const int gx = gridDim.x;
    const int nwg = gx * gridDim.y;
    const int lin = blockIdx.y * gx + blockIdx.x;
    if ((nwg & 7) == 0) {
      const int q = nwg >> 3;
      const int nl = (lin & 7) * q + (lin >> 3);
      blkN = nl % gx;
      blkM = nl / gx;
    } else {
      blkN = blockIdx.x;
      blkM = blockIdx.y;
    }
  }

  const int tid = threadIdx.x;
  const int w = tid >> 6, lane = tid & 63;
  const int wr = w >> 2, wc = w & 3;
  const int lrow = lane & 15, lhi = lane >> 4;

  const TIN* Abase = Ag + (size_t)blkM * 128 * lda;
  const TIN* Bbase = Bg + (size_t)blkN * 128 * ldb;

  f32x4 acc[4][2] = {};
  f32x4 rs[4] = {};
  vec8 ones;
  if (EPI == 2) {
#pragma unroll
    for (int i = 0; i < 8; ++i) ones[i] = (TIN)1.0f;
  }

  for (int kt = k0; kt < k0 + K; kt += 64) {
#pragma unroll
    for (int it = 0; it < 2; ++it) {
      int grp = it * 8 + w;                 // 0..15, wave-uniform
      int chunk = grp * 64 + lane;          // 16B chunks
      int row = chunk >> 3;
      int col = (chunk & 7) << 3;
      gload_lds16(Abase + (size_t)row * lda + kt + col, (char*)As + (size_t)grp * 1024);
      gload_lds16(Bbase + (size_t)row * ldb + kt + col, (char*)Bs + (size_t)grp * 1024);
    }
    __syncthreads();

    vec8 af[4][2], bfr[2][2];
#pragma unroll
    for (int m = 0; m < 4; ++m)
#pragma unroll
      for (int kk = 0; kk < 2; ++kk)
        af[m][kk] = *(const vec8*)&As[(wr * 64 + m * 16 + lrow) * 64 + kk * 32 + lhi * 8];
#pragma unroll
    for (int n = 0; n < 2; ++n)
#pragma unroll
      for (int kk = 0; kk < 2; ++kk)
        bfr[n][kk] = *(const vec8*)&Bs[(wc * 32 + n * 16 + lrow) * 64 + kk * 32 + lhi * 8];

#pragma unroll
    for (int m = 0; m < 4; ++m)
#pragma unroll
      for (int n = 0; n < 2; ++n)
#pragma unroll
        for (int kk = 0; kk < 2; ++kk)
          acc[m][n] = mfma16(af[m][kk], bfr[n][kk], acc[m][n]);

    if (EPI == 2 && wc == 0) {
#pragma unroll
      for (int m = 0; m < 4; ++m)
#pragma unroll
        for (int kk = 0; kk < 2; ++kk)
          rs[m] = mfma16(af[m][kk], ones, rs[m]);
    }
    __syncthreads();
  }

  const int row0 = blkM * 128 + wr * 64;
  const int col0 = blkN * 128 + wc * 32;
  const int sbf = args.storebf[z];
#pragma unroll
  for (int m = 0; m < 4; ++m) {
#pragma unroll
    for (int n = 0; n < 2; ++n) {
#pragma unroll
      for (int r = 0; r < 4; ++r) {
        int row = row0 + m * 16 + lhi * 4 + r;
        int col = col0 + n * 16 + lrow;
        float v = acc[m][n][r];
        if (EPI == 0) {
          if (sbf)
            ((bf16*)Cg)[(size_t)row * ldc + col] = (bf16)(v + bias[col]);
          else
            ((f16*)Cg)[(size_t)row * ldc + col] = (f16)(v + bias[col]);
        } else if (EPI == 1) {
          ((bf16*)Cg)[(size_t)row * ldc + col] = (bf16)__expf(v);
        } else if (EPI == 2) {
          ((float*)Cg)[(size_t)row * ldc + col] = v;
        } else {
          ((float*)Cg)[(size_t)row * ldc + col] = v + bias[col];
        }
      }
    }
  }
  if (EPI == 2 && wc == 0 && lrow == 0) {
    float* rsO = args.rsO[z];
#pragma unroll
    for (int m = 0; m < 4; ++m)
#pragma unroll
      for (int r = 0; r < 4; ++r)
        rsO[row0 + m * 16 + lhi * 4 + r] = rs[m][r];
  }
}

// ---------------- launch ----------------

extern "C" void kernel_launch(void* const* d_in, const int* in_sizes, int n_in,
                              void* d_out, int out_size, void* d_ws, size_t ws_size,
                              hipStream_t stream) {
  const float* in1 = (const float*)d_in[0];
  const float* in2 = (const float*)d_in[1];
  const float* Wq = (const float*)d_in[2];
  const float* bq = (const float*)d_in[3];
  const float* Wk = (const float*)d_in[4];
  const float* bk = (const float*)d_in[5];
  const float* Wv = (const float*)d_in[6];
  const float* bv = (const float*)d_in[7];
  const float* Wo = (const float*)d_in[8];
  const float* bo = (const float*)d_in[9];
  float* out = (float*)d_out;

  const size_t IN_E = (size_t)NROWS * DIN;   // 4M
  const size_t WT_E = (size_t)DA * DIN;      // 512K
  const size_t QS = (size_t)NROWS * DA;      // 2M
  const size_t PS = (size_t)NROWS * NROWS;   // 16M

  f16* qk = (f16*)d_ws;                      // 4*QS f16 = 16 MB (dead after exp GEMM)
  f16* in_hf = qk + 4 * QS;                  // 2*IN_E f16 = 16 MB (dead after proj)
  bf16* vv = (bf16*)(in_hf + 2 * IN_E);      // 2*QS bf16 = 8 MB (dead after transpose)
  f16* wt = (f16*)(vv + 2 * QS);             // 3*WT_E f16 = 3 MB
  f16* woT = wt + 3 * WT_E;                  // WT_E f16 = 1 MB (live till end)
  bf16* vt = (bf16*)(woT + WT_E);            // 2*QS bf16 = 8 MB
  bf16* P = vt + 2 * QS;                     // 2*PS bf16 = 64 MB
  f16* mid = (f16*)(P + 2 * PS);             // 2*QS f16 = 8 MB
  float* pO = (float*)d_ws;                  // aliases qk+in_hf: 4*QS f32 = 32 MB
  float* prs = (float*)vv;                   // aliases vv: 4*NROWS f32 = 64 KB

  // 1. cast inputs to fp16
  cast_kernel<<<dim3((unsigned)(IN_E / 1024), 1, 2), dim3(256), 0, stream>>>(
      in1, in2, in_hf, in_hf + IN_E, (int)IN_E);

  // 2. transpose-cast weights
  transpose_f32<<<dim3(DA / 32, DIN / 32, 3), dim3(32, 8), 0, stream>>>(
      Wq, Wk, Wv, wt, WT_E, DIN, DA);
  transpose_f32<<<dim3(DIN / 32, DA / 32, 1), dim3(32, 8), 0, stream>>>(
      Wo, Wo, Wo, woT, 0, DA, DIN);

  // 3. projections, z = Q1,K1,Q2,K2,V1,V2 (V stored bf16)
  {
    GArgs<f16> a{};
    const float* bs[3] = {bq, bk, bv};
    for (int zi = 0; zi < 6; ++zi) {
      int which = (zi < 4) ? (zi & 1) : 2;        // wq/wk/wv
      int src = (zi < 4) ? (zi >> 1) : (zi - 4);  // input1/input2
      a.A[zi] = in_hf + (size_t)src * IN_E;
      a.B[zi] = wt + (size_t)which * WT_E;
      a.bias[zi] = bs[which];
      a.C[zi] = (zi < 4) ? (void*)(qk + (size_t)zi * QS) : (void*)(vv + (size_t)(zi - 4) * QS);
      a.storebf[zi] = (zi >= 4);
    }
    a.K = DIN; a.lda = DIN; a.ldb = DIN; a.ldc = DA;
    gemm_bt<f16, f16, 0><<<dim3(DA / 128, NROWS / 128, 6), dim3(512), 0, stream>>>(a);
  }

  // 4. V -> Vt ([4096,512] -> [512][4096])
  transpose_b16<<<dim3(DA / 32, NROWS / 32, 2), dim3(32, 8), 0, stream>>>(
      vv, QS, vt, QS, NROWS, DA);

  // 5. P = exp(Q @ K^T): z=0: Q1@K2^T, z=1: Q2@K1^T (bf16 out)
  {
    GArgs<f16> a{};
    a.A[0] = qk + 0 * QS; a.B[0] = qk + 3 * QS; a.C[0] = P;
    a.A[1] = qk + 2 * QS; a.B[1] = qk + 1 * QS; a.C[1] = P + PS;
    a.K = DA; a.lda = DA; a.ldb = DA; a.ldc = NROWS;
    gemm_bt<f16, bf16, 1><<<dim3(NROWS / 128, NROWS / 128, 2), dim3(512), 0, stream>>>(a);
  }

  // 6. PV split-K partials: z encodes (s = z>>1, pair = z&1)
  {
    GArgs<bf16> a{};
    for (int i = 0; i < 4; ++i) {
      int pair = i & 1, s = i >> 1;
      a.A[i] = P + (size_t)pair * PS;
      a.B[i] = vt + (size_t)(pair ^ 1) * QS;
      a.C[i] = pO + (size_t)i * QS;
      a.rsO[i] = prs + (size_t)i * NROWS;
      a.k0[i] = s * 2048;
    }
    a.K = 2048; a.lda = NROWS; a.ldb = NROWS; a.ldc = DA;
    gemm_bt<bf16, float, 2><<<dim3(DA / 128, NROWS / 128, 4), dim3(512), 0, stream>>>(a);
  }

  // 7. merge partials -> mid (f16)
  merge_kernel<<<dim3((unsigned)(2 * QS / 1024)), dim3(256), 0, stream>>>(pO, prs, mid);

  // 8. out = mid @ Wo + bo (f32)
  {
    GArgs<f16> a{};
    a.A[0] = mid;      a.C[0] = out;
    a.A[1] = mid + QS; a.C[1] = out + (size_t)NROWS * DIN;
    a.B[0] = a.B[1] = woT;
    a.bias[0] = a.bias[1] = bo;
    a.K = DA; a.lda = DA; a.ldb = DA; a.ldc = DIN;
    gemm_bt<f16, float, 3><<<dim3(DIN / 128, NROWS / 128, 2), dim3(512), 0, stream>>>(a);
  }
}